// Round 2
// baseline (15.504 us; speedup 1.0000x reference)
//
#include <hip/hip_runtime.h>
#include <hip/hip_bf16.h>
#include <math.h>

// 4-wire quantum circuit, B=262144.
// Algebraic reduction:
//   state = U * psi(x), psi real product state; U = fixed 20-op layer (theta-only).
//   z0 = cos(y0)*psi^T ReA psi + sin(y0)*psi^T ReB psi,
//     A = U^dag Z0 U,  B = U^dag X0 U  (both Hermitian -> Re parts symmetric).
//   Second-encoder rotations on wires 1..3 commute with Z0 and cancel.
// Prep kernel (1 block) builds packed symmetric ReA/ReB (136 floats each,
// off-diagonals pre-doubled) into d_ws; main kernel does two quadratic forms
// with batch-uniform matrix operands (compiler -> s_load, scalar pipe).

template<int W>
__device__ __forceinline__ void apply_ry(float (&sr)[16], float (&si)[16], float c, float s) {
    constexpr int bit = 1 << (3 - W);
    #pragma unroll
    for (int i = 0; i < 16; ++i) {
        if (!(i & bit)) {
            const int j = i | bit;
            float ar = sr[i], ai = si[i], br = sr[j], bi = si[j];
            sr[i] = c * ar - s * br;  si[i] = c * ai - s * bi;
            sr[j] = s * ar + c * br;  si[j] = s * ai + c * bi;
        }
    }
}

template<int W>
__device__ __forceinline__ void apply_rx(float (&sr)[16], float (&si)[16], float c, float s) {
    constexpr int bit = 1 << (3 - W);
    #pragma unroll
    for (int i = 0; i < 16; ++i) {
        if (!(i & bit)) {
            const int j = i | bit;
            float ar = sr[i], ai = si[i], br = sr[j], bi = si[j];
            sr[i] = c * ar + s * bi;  si[i] = c * ai - s * br;
            sr[j] = c * br + s * ai;  si[j] = c * bi - s * ar;
        }
    }
}

template<int W>
__device__ __forceinline__ void apply_rz(float (&sr)[16], float (&si)[16], float c, float s) {
    constexpr int bit = 1 << (3 - W);
    #pragma unroll
    for (int i = 0; i < 16; ++i) {
        if (!(i & bit)) {
            const int j = i | bit;
            float ar = sr[i], ai = si[i], br = sr[j], bi = si[j];
            sr[i] = c * ar + s * ai;  si[i] = c * ai - s * ar;
            sr[j] = c * br - s * bi;  si[j] = c * bi + s * br;
        }
    }
}

template<int C>
__device__ __forceinline__ void apply_cnot(float (&sr)[16], float (&si)[16]) {
    constexpr int cb = 1 << (3 - C);
    constexpr int tb = 1 << (2 - C);
    #pragma unroll
    for (int i = 0; i < 16; ++i) {
        if ((i & cb) && !(i & tb)) {
            const int j = i | tb;
            float t;
            t = sr[i]; sr[i] = sr[j]; sr[j] = t;
            t = si[i]; si[i] = si[j]; si[j] = t;
        }
    }
}

// ---- prep: build packed ReA/ReB into ws[0..135], ws[136..271] ----
__global__ __launch_bounds__(256) void qprep_kernel(
        const float* __restrict__ theta, float* __restrict__ ws) {
    __shared__ float Ur[16][16], Ui[16][16];   // [row k][col t]
    int t = threadIdx.x;
    if (t < 16) {
        float sr[16], si[16];
        #pragma unroll
        for (int i = 0; i < 16; ++i) { sr[i] = (i == t) ? 1.0f : 0.0f; si[i] = 0.0f; }
        float tc, ts;
        #define ROT(IDX, FN, W) do { \
            __sincosf(0.5f * theta[IDX], &ts, &tc); \
            FN<W>(sr, si, tc, ts); \
        } while (0)
        ROT(0,  apply_rx, 3); ROT(1,  apply_ry, 2); ROT(2,  apply_rz, 1);
        apply_cnot<0>(sr, si);
        ROT(4,  apply_rx, 3); ROT(5,  apply_ry, 2); ROT(6,  apply_rz, 1);
        apply_cnot<1>(sr, si);
        ROT(8,  apply_rx, 3); ROT(9,  apply_ry, 2); ROT(10, apply_rz, 1);
        apply_cnot<2>(sr, si);
        ROT(12, apply_rx, 3); ROT(13, apply_ry, 2); ROT(14, apply_rz, 1);
        apply_cnot<0>(sr, si);
        ROT(16, apply_rx, 3); ROT(17, apply_ry, 2); ROT(18, apply_rz, 1);
        apply_cnot<1>(sr, si);
        #undef ROT
        #pragma unroll
        for (int k = 0; k < 16; ++k) { Ur[k][t] = sr[k]; Ui[k][t] = si[k]; }
    }
    __syncthreads();
    if (t < 136) {
        // unpack t -> (i,j), i<=j, row i holds 16-i entries
        int p = t, i = 0, len = 16;
        while (p >= len) { p -= len; --len; ++i; }
        int j = i + p;
        float sa = 0.0f, sb = 0.0f;
        #pragma unroll
        for (int k = 0; k < 16; ++k) {
            float uri = Ur[k][i], uii = Ui[k][i];
            float zr  = Ur[k][j], zi  = Ui[k][j];
            float xr  = Ur[k ^ 8][j], xi = Ui[k ^ 8][j];
            float sgn = (k < 8) ? 1.0f : -1.0f;
            sa += sgn * (uri * zr + uii * zi);   // Re(U^dag Z0 U)_ij
            sb += uri * xr + uii * xi;           // Re(U^dag X0 U)_ij
        }
        float w = (i == j) ? 1.0f : 2.0f;        // fold symmetry factor
        ws[t]       = w * sa;
        ws[136 + t] = w * sb;
    }
}

// ---- main: per-batch quadratic forms ----
__global__ __launch_bounds__(256) void qmain_kernel(
        const float* __restrict__ x,
        const float* __restrict__ y,
        const float* __restrict__ ws,
        float* __restrict__ out,
        int B) {
    int b = blockIdx.x * blockDim.x + threadIdx.x;
    if (b >= B) return;

    float4 xv = reinterpret_cast<const float4*>(x)[b];
    float y0  = reinterpret_cast<const float4*>(y)[b].x;

    float c0, s0, c1, s1, c2, s2, c3, s3;
    __sincosf(0.5f * xv.x, &s0, &c0);
    __sincosf(0.5f * xv.y, &s1, &c1);
    __sincosf(0.5f * xv.z, &s2, &c2);
    __sincosf(0.5f * xv.w, &s3, &c3);

    // psi[i] via two-level product tree (wire0=bit3 ... wire3=bit0)
    float q0[4] = { c0 * c1, c0 * s1, s0 * c1, s0 * s1 };
    float q1[4] = { c2 * c3, c2 * s3, s2 * c3, s2 * s3 };
    float psi[16];
    #pragma unroll
    for (int i = 0; i < 16; ++i) psi[i] = q0[i >> 2] * q1[i & 3];

    const float* A  = ws;
    const float* Bm = ws + 136;
    float a = 0.0f, bb = 0.0f;
    int p = 0;
    #pragma unroll
    for (int i = 0; i < 16; ++i) {
        #pragma unroll
        for (int j = i; j < 16; ++j) {
            float t2 = psi[i] * psi[j];
            a  = fmaf(A[p],  t2, a);    // A[p]/Bm[p] uniform -> s_load
            bb = fmaf(Bm[p], t2, bb);
            ++p;
        }
    }

    float cy, sy;
    __sincosf(y0, &sy, &cy);
    out[b] = fabsf(cy * a + sy * bb);
}

extern "C" void kernel_launch(void* const* d_in, const int* in_sizes, int n_in,
                              void* d_out, int out_size, void* d_ws, size_t ws_size,
                              hipStream_t stream) {
    const float* x     = (const float*)d_in[0];
    const float* y     = (const float*)d_in[1];
    const float* theta = (const float*)d_in[2];
    float* out = (float*)d_out;
    float* ws  = (float*)d_ws;

    int B = out_size;  // 262144
    qprep_kernel<<<1, 256, 0, stream>>>(theta, ws);
    int block = 256;
    int grid = (B + block - 1) / block;
    qmain_kernel<<<grid, block, 0, stream>>>(x, y, ws, out, B);
}

// Round 3
// 13.448 us; speedup vs baseline: 1.1529x; 1.1529x over previous
//
#include <hip/hip_runtime.h>
#include <hip/hip_bf16.h>
#include <math.h>

// 4-wire quantum circuit, B=262144 — single fused kernel.
//
// Reduction chain:
//   state = U * psi(x); psi = tensor product of (cos(x_w/2), sin(x_w/2)).
//   z0 = cos(y0) * psi^T A psi + sin(y0) * psi^T B psi,
//     A = Re(U^dag Z0 U), B = Re(U^dag X0 U)  (y wires 1..3 cancel vs Z0).
//   psi_i psi_j factorizes per wire into {c^2, cs, s^2} = affine in
//   {1, cos x_w, sin x_w}  =>  each quadratic form is a 3^4-coefficient
//   trig-polynomial tensor; evaluation = nested contraction, 80 FMA/tensor.
//
// Per block: threads 0..15 build U columns (LDS), 256 threads build S_ij,
// 81 threads gather the 3^4 tensors + basis transform, then every thread
// evaluates its batch element from LDS (uniform-address broadcast reads).

template<int W>
__device__ __forceinline__ void apply_ry(float (&sr)[16], float (&si)[16], float c, float s) {
    constexpr int bit = 1 << (3 - W);
    #pragma unroll
    for (int i = 0; i < 16; ++i) {
        if (!(i & bit)) {
            const int j = i | bit;
            float ar = sr[i], ai = si[i], br = sr[j], bi = si[j];
            sr[i] = c * ar - s * br;  si[i] = c * ai - s * bi;
            sr[j] = s * ar + c * br;  si[j] = s * ai + c * bi;
        }
    }
}

template<int W>
__device__ __forceinline__ void apply_rx(float (&sr)[16], float (&si)[16], float c, float s) {
    constexpr int bit = 1 << (3 - W);
    #pragma unroll
    for (int i = 0; i < 16; ++i) {
        if (!(i & bit)) {
            const int j = i | bit;
            float ar = sr[i], ai = si[i], br = sr[j], bi = si[j];
            sr[i] = c * ar + s * bi;  si[i] = c * ai - s * br;
            sr[j] = c * br + s * ai;  si[j] = c * bi - s * ar;
        }
    }
}

template<int W>
__device__ __forceinline__ void apply_rz(float (&sr)[16], float (&si)[16], float c, float s) {
    constexpr int bit = 1 << (3 - W);
    #pragma unroll
    for (int i = 0; i < 16; ++i) {
        if (!(i & bit)) {
            const int j = i | bit;
            float ar = sr[i], ai = si[i], br = sr[j], bi = si[j];
            sr[i] = c * ar + s * ai;  si[i] = c * ai - s * ar;
            sr[j] = c * br - s * bi;  si[j] = c * bi + s * br;
        }
    }
}

template<int C>
__device__ __forceinline__ void apply_cnot(float (&sr)[16], float (&si)[16]) {
    constexpr int cb = 1 << (3 - C);
    constexpr int tb = 1 << (2 - C);
    #pragma unroll
    for (int i = 0; i < 16; ++i) {
        if ((i & cb) && !(i & tb)) {
            const int j = i | tb;
            float t;
            t = sr[i]; sr[i] = sr[j]; sr[j] = t;
            t = si[i]; si[i] = si[j]; si[j] = t;
        }
    }
}

__device__ __forceinline__ void tri_transform(volatile float* T, int base, int s) {
    // basis change (c^2, cs, s^2) -> (1, cos, sin) along one tensor axis:
    // c^2 = (1+cos)/2, s^2 = (1-cos)/2, cs = sin/2
    float x0 = T[base], x1 = T[base + s], x2 = T[base + 2 * s];
    T[base]         = 0.5f * (x0 + x2);
    T[base + s]     = 0.5f * (x0 - x2);
    T[base + 2 * s] = 0.5f * x1;
}

__global__ __launch_bounds__(256, 4) void qfused_kernel(
        const float* __restrict__ x,
        const float* __restrict__ y,
        const float* __restrict__ theta,
        float* __restrict__ out,
        int B) {
    __shared__ float Ur[16][16], Ui[16][16];   // [row k][col]
    __shared__ float SA[256], SB[256];         // S_ij packed i*16+j
    __shared__ float TA[81], TB[81];           // 3^4 trig tensors

    const int t = threadIdx.x;

    // ---- Phase 0: build U columns (16 threads, theta uniform) ----
    if (t < 16) {
        float sr[16], si[16];
        #pragma unroll
        for (int i = 0; i < 16; ++i) { sr[i] = (i == t) ? 1.0f : 0.0f; si[i] = 0.0f; }
        float tc, ts;
        #define ROT(IDX, FN, W) do { \
            __sincosf(0.5f * theta[IDX], &ts, &tc); \
            FN<W>(sr, si, tc, ts); \
        } while (0)
        ROT(0,  apply_rx, 3); ROT(1,  apply_ry, 2); ROT(2,  apply_rz, 1);
        apply_cnot<0>(sr, si);
        ROT(4,  apply_rx, 3); ROT(5,  apply_ry, 2); ROT(6,  apply_rz, 1);
        apply_cnot<1>(sr, si);
        ROT(8,  apply_rx, 3); ROT(9,  apply_ry, 2); ROT(10, apply_rz, 1);
        apply_cnot<2>(sr, si);
        ROT(12, apply_rx, 3); ROT(13, apply_ry, 2); ROT(14, apply_rz, 1);
        apply_cnot<0>(sr, si);
        ROT(16, apply_rx, 3); ROT(17, apply_ry, 2); ROT(18, apply_rz, 1);
        apply_cnot<1>(sr, si);
        #undef ROT
        #pragma unroll
        for (int k = 0; k < 16; ++k) { Ur[k][t] = sr[k]; Ui[k][t] = si[k]; }
    }
    __syncthreads();

    // ---- Phase A: S_ij = Re(U^dag Z0 U)_ij and Re(U^dag X0 U)_ij ----
    {
        const int i = t >> 4, j = t & 15;
        float a = 0.0f, b = 0.0f;
        #pragma unroll
        for (int k = 0; k < 16; ++k) {
            float uri = Ur[k][i], uii = Ui[k][i];
            float zr  = Ur[k][j], zi  = Ui[k][j];
            float xr  = Ur[k ^ 8][j], xi = Ui[k ^ 8][j];
            float srn = (k < 8) ? uri : -uri;
            float sin_ = (k < 8) ? uii : -uii;
            a = fmaf(srn, zr, a);  a = fmaf(sin_, zi, a);
            b = fmaf(uri, xr, b);  b = fmaf(uii, xi, b);
        }
        SA[t] = a; SB[t] = b;
    }
    __syncthreads();

    // ---- Phase B: gather into 3^4 tensor (digit d_w = bit_w(i)+bit_w(j)) ----
    if (t < 81) {
        int d0 = t / 27, r = t % 27;
        int d1 = r / 9,  d2 = (r / 3) % 3, d3 = r % 3;
        int ones = ((d0 == 1) << 3) | ((d1 == 1) << 2) | ((d2 == 1) << 1) | (d3 == 1);
        int twos = ((d0 == 2) << 3) | ((d1 == 2) << 2) | ((d2 == 2) << 1) | (d3 == 2);
        float a = 0.0f, b = 0.0f;
        #pragma unroll
        for (int c = 0; c < 16; ++c) {
            if (c & ~ones) continue;
            int i = twos | c;
            int j = twos | (ones & ~c);
            a += SA[i * 16 + j];
            b += SB[i * 16 + j];
        }
        TA[t] = a; TB[t] = b;
    }
    __syncthreads();

    // ---- Phase C: basis transform along each of the 4 axes ----
    if (t < 27) { tri_transform(TA, t, 27); tri_transform(TB, t, 27); }
    __syncthreads();
    if (t < 27) {
        int base = 27 * (t / 9) + (t % 9);
        tri_transform(TA, base, 9); tri_transform(TB, base, 9);
    }
    __syncthreads();
    if (t < 27) {
        int base = 27 * (t / 9) + 9 * ((t % 9) / 3) + (t % 3);
        tri_transform(TA, base, 3); tri_transform(TB, base, 3);
    }
    __syncthreads();
    if (t < 27) {
        int base = 27 * (t / 9) + 9 * ((t % 9) / 3) + 3 * (t % 3);
        tri_transform(TA, base, 1); tri_transform(TB, base, 1);
    }
    __syncthreads();

    // ---- Phase D: per-thread evaluation ----
    int b = blockIdx.x * 256 + t;
    if (b >= B) return;

    float4 xv = reinterpret_cast<const float4*>(x)[b];
    float y0  = reinterpret_cast<const float4*>(y)[b].x;

    float cx0, sx0, cx1, sx1, cx2, sx2, cx3, sx3;
    __sincosf(xv.x, &sx0, &cx0);
    __sincosf(xv.y, &sx1, &cx1);
    __sincosf(xv.z, &sx2, &cx2);
    __sincosf(xv.w, &sx3, &cx3);

    float ra[27], rb[27];
    #pragma unroll
    for (int m = 0; m < 27; ++m) {
        ra[m] = fmaf(sx3, TA[3 * m + 2], fmaf(cx3, TA[3 * m + 1], TA[3 * m]));
        rb[m] = fmaf(sx3, TB[3 * m + 2], fmaf(cx3, TB[3 * m + 1], TB[3 * m]));
    }
    float qa[9], qb[9];
    #pragma unroll
    for (int m = 0; m < 9; ++m) {
        qa[m] = fmaf(sx2, ra[3 * m + 2], fmaf(cx2, ra[3 * m + 1], ra[3 * m]));
        qb[m] = fmaf(sx2, rb[3 * m + 2], fmaf(cx2, rb[3 * m + 1], rb[3 * m]));
    }
    float pa[3], pb[3];
    #pragma unroll
    for (int m = 0; m < 3; ++m) {
        pa[m] = fmaf(sx1, qa[3 * m + 2], fmaf(cx1, qa[3 * m + 1], qa[3 * m]));
        pb[m] = fmaf(sx1, qb[3 * m + 2], fmaf(cx1, qb[3 * m + 1], qb[3 * m]));
    }
    float a  = fmaf(sx0, pa[2], fmaf(cx0, pa[1], pa[0]));
    float bb = fmaf(sx0, pb[2], fmaf(cx0, pb[1], pb[0]));

    float cy, sy;
    __sincosf(y0, &sy, &cy);
    out[b] = fabsf(fmaf(sy, bb, cy * a));
}

extern "C" void kernel_launch(void* const* d_in, const int* in_sizes, int n_in,
                              void* d_out, int out_size, void* d_ws, size_t ws_size,
                              hipStream_t stream) {
    const float* x     = (const float*)d_in[0];
    const float* y     = (const float*)d_in[1];
    const float* theta = (const float*)d_in[2];
    float* out = (float*)d_out;

    int B = out_size;  // 262144
    int block = 256;
    int grid = (B + block - 1) / block;
    qfused_kernel<<<grid, block, 0, stream>>>(x, y, theta, out, B);
}

// Round 4
// 9.765 us; speedup vs baseline: 1.5877x; 1.3772x over previous
//
#include <hip/hip_runtime.h>
#include <hip/hip_bf16.h>
#include <math.h>

// 4-wire quantum circuit, B=262144 — single fused kernel, v4.
//
// Wire 0 is never rotated (rotation wires (3i+3)%4 ∈ {1,2,3}) and is only a
// CNOT control => U = diag(U00, U11) in the wire-0 basis, with U00/U11 the
// 8x8 wire-1..3 circuits where CNOT(0,1) -> I / X1.
//   U^dag Z0 U = Z0            =>  <Z0> = cos(x0)
//   U^dag X0 U = [[0,M],[M^dag,0]], M = U00^dag U11
//                              =>  <X0> = sin(x0) * psi123^T Re(M) psi123
//   out = | cos(y0) cos(x0) + sin(y0) sin(x0) * g(x1,x2,x3) |
// g = 27-coefficient tensor over basis (1, cos x_w, sin x_w) per wire.
// (Second-encoder wires 1..3 cancel against Z0/X0 on wire 0.)

// 3-wire (8-dim) gate helpers; wire w in {1,2,3} <-> bit (3-w) in {2,1,0}.
template<int BIT>
__device__ __forceinline__ void rx8(float (&sr)[8], float (&si)[8], float c, float s) {
    #pragma unroll
    for (int i = 0; i < 8; ++i) {
        if (!(i & (1 << BIT))) {
            const int j = i | (1 << BIT);
            float ar = sr[i], ai = si[i], br = sr[j], bi = si[j];
            sr[i] = c * ar + s * bi;  si[i] = c * ai - s * br;
            sr[j] = c * br + s * ai;  si[j] = c * bi - s * ar;
        }
    }
}

template<int BIT>
__device__ __forceinline__ void ry8(float (&sr)[8], float (&si)[8], float c, float s) {
    #pragma unroll
    for (int i = 0; i < 8; ++i) {
        if (!(i & (1 << BIT))) {
            const int j = i | (1 << BIT);
            float ar = sr[i], ai = si[i], br = sr[j], bi = si[j];
            sr[i] = c * ar - s * br;  si[i] = c * ai - s * bi;
            sr[j] = s * ar + c * br;  si[j] = s * ai + c * bi;
        }
    }
}

template<int BIT>
__device__ __forceinline__ void rz8(float (&sr)[8], float (&si)[8], float c, float s) {
    #pragma unroll
    for (int i = 0; i < 8; ++i) {
        if (!(i & (1 << BIT))) {
            const int j = i | (1 << BIT);
            float ar = sr[i], ai = si[i], br = sr[j], bi = si[j];
            sr[i] = c * ar + s * ai;  si[i] = c * ai - s * ar;
            sr[j] = c * br - s * bi;  si[j] = c * bi + s * br;
        }
    }
}

template<int CB, int TB>
__device__ __forceinline__ void cnot8(float (&sr)[8], float (&si)[8]) {
    #pragma unroll
    for (int i = 0; i < 8; ++i) {
        if ((i & (1 << CB)) && !(i & (1 << TB))) {
            const int j = i | (1 << TB);
            float t;
            t = sr[i]; sr[i] = sr[j]; sr[j] = t;
            t = si[i]; si[i] = si[j]; si[j] = t;
        }
    }
}

__device__ __forceinline__ void x1_8(float (&sr)[8], float (&si)[8]) {
    #pragma unroll
    for (int i = 0; i < 4; ++i) {          // flip bit2: i <-> i+4
        const int j = i + 4;
        float t;
        t = sr[i]; sr[i] = sr[j]; sr[j] = t;
        t = si[i]; si[i] = si[j]; si[j] = t;
    }
}

__device__ __forceinline__ void tri_transform(volatile float* T, int base, int s) {
    // axis basis change (c^2, cs, s^2) -> (1, cos, sin):
    float x0 = T[base], x1 = T[base + s], x2 = T[base + 2 * s];
    T[base]         = 0.5f * (x0 + x2);
    T[base + s]     = 0.5f * (x0 - x2);
    T[base + 2 * s] = 0.5f * x1;
}

__global__ __launch_bounds__(256) void qfused_kernel(
        const float* __restrict__ x,
        const float* __restrict__ y,
        const float* __restrict__ theta,
        float* __restrict__ out,
        int B) {
    __shared__ float Vr[2][8][8], Vi[2][8][8];   // [blk][row k][col]
    __shared__ float Nm[64];                     // Re(U00^dag U11), row-major
    __shared__ float T[27];                      // trig tensor

    const int t = threadIdx.x;

    // ---- Phase 0: evolve 8 basis columns through U00 (blk=0) / U11 (blk=1) ----
    if (t < 16) {
        const int col = t & 7, blk = t >> 3;
        float sr[8], si[8];
        #pragma unroll
        for (int i = 0; i < 8; ++i) { sr[i] = (i == col) ? 1.0f : 0.0f; si[i] = 0.0f; }
        float tc, ts;
        #define ROT(IDX, FN, BIT) do { \
            __sincosf(0.5f * theta[IDX], &ts, &tc); \
            FN<BIT>(sr, si, tc, ts); \
        } while (0)
        ROT(0, rx8, 0); ROT(1, ry8, 1); ROT(2, rz8, 2);
        if (blk) x1_8(sr, si);                 // CNOT(0,1): wire0=|1> block
        ROT(4, rx8, 0); ROT(5, ry8, 1); ROT(6, rz8, 2);
        cnot8<2, 1>(sr, si);                   // CNOT(1,2)
        ROT(8, rx8, 0); ROT(9, ry8, 1); ROT(10, rz8, 2);
        cnot8<1, 0>(sr, si);                   // CNOT(2,3)
        ROT(12, rx8, 0); ROT(13, ry8, 1); ROT(14, rz8, 2);
        if (blk) x1_8(sr, si);                 // CNOT(0,1)
        ROT(16, rx8, 0); ROT(17, ry8, 1); ROT(18, rz8, 2);
        cnot8<2, 1>(sr, si);                   // CNOT(1,2)
        #undef ROT
        #pragma unroll
        for (int k = 0; k < 8; ++k) { Vr[blk][k][col] = sr[k]; Vi[blk][k][col] = si[k]; }
    }
    __syncthreads();

    // ---- Phase A: N_ij = sum_k Re(conj(U00[k,i]) * U11[k,j]) ----
    if (t < 64) {
        const int i = t >> 3, j = t & 7;
        float a = 0.0f;
        #pragma unroll
        for (int k = 0; k < 8; ++k) {
            a = fmaf(Vr[0][k][i], Vr[1][k][j], a);
            a = fmaf(Vi[0][k][i], Vi[1][k][j], a);
        }
        Nm[t] = a;
    }
    __syncthreads();

    // ---- Phase B: gather into 3^3 tensor (digit d_w = bit_w(i)+bit_w(j)) ----
    if (t < 27) {
        const int d1 = t / 9, d2 = (t / 3) % 3, d3 = t % 3;
        const int ones = ((d1 == 1) << 2) | ((d2 == 1) << 1) | (d3 == 1);
        const int twos = ((d1 == 2) << 2) | ((d2 == 2) << 1) | (d3 == 2);
        float a = 0.0f;
        #pragma unroll
        for (int c = 0; c < 8; ++c) {
            if (c & ~ones) continue;
            a += Nm[(twos | c) * 8 + (twos | (ones & ~c))];
        }
        T[t] = a;
    }
    __syncthreads();

    // ---- Phase C: basis transform along the 3 axes ----
    if (t < 9) tri_transform(T, t, 9);
    __syncthreads();
    if (t < 9) tri_transform(T, 9 * (t / 3) + (t % 3), 3);
    __syncthreads();
    if (t < 9) tri_transform(T, 3 * t, 1);
    __syncthreads();

    // ---- Eval: one batch element per thread ----
    const int b = blockIdx.x * 256 + t;
    if (b >= B) return;

    float4 xv = reinterpret_cast<const float4*>(x)[b];
    float y0  = reinterpret_cast<const float4*>(y)[b].x;

    float cx0, sx0, cx1, sx1, cx2, sx2, cx3, sx3, cy, sy;
    __sincosf(xv.x, &sx0, &cx0);
    __sincosf(xv.y, &sx1, &cx1);
    __sincosf(xv.z, &sx2, &cx2);
    __sincosf(xv.w, &sx3, &cx3);
    __sincosf(y0,   &sy,  &cy);

    float r3[9];
    #pragma unroll
    for (int m = 0; m < 9; ++m)
        r3[m] = fmaf(sx3, T[3 * m + 2], fmaf(cx3, T[3 * m + 1], T[3 * m]));
    float r2[3];
    #pragma unroll
    for (int m = 0; m < 3; ++m)
        r2[m] = fmaf(sx2, r3[3 * m + 2], fmaf(cx2, r3[3 * m + 1], r3[3 * m]));
    float g = fmaf(sx1, r2[2], fmaf(cx1, r2[1], r2[0]));

    out[b] = fabsf(fmaf(cy, cx0, sy * sx0 * g));
}

extern "C" void kernel_launch(void* const* d_in, const int* in_sizes, int n_in,
                              void* d_out, int out_size, void* d_ws, size_t ws_size,
                              hipStream_t stream) {
    const float* x     = (const float*)d_in[0];
    const float* y     = (const float*)d_in[1];
    const float* theta = (const float*)d_in[2];
    float* out = (float*)d_out;

    int B = out_size;  // 262144
    int block = 256;
    int grid = (B + block - 1) / block;
    qfused_kernel<<<grid, block, 0, stream>>>(x, y, theta, out, B);
}